// Round 2
// baseline (71.273 us; speedup 1.0000x reference)
//
#include <hip/hip_runtime.h>
#include <hip/hip_bf16.h>

#define B_ 4
#define T_ 800
#define U_ 150
#define D_ 512
#define H_ 256
#define PADH 260   // row stride (floats); 260%32==4 -> worst aliasing 2-way (free)

static constexpr float ARG_SCALE = 2.8853900817779268f; // 2/ln(2): tanh(x)=1-2/(1+2^(c*x))
static constexpr float LOG2E_F   = 1.4426950408889634f;

extern "C" __device__ float __ocml_exp2_f32(float);

__device__ __forceinline__ float fast_exp2(float x) {
#if __has_builtin(__builtin_amdgcn_exp2f)
    return __builtin_amdgcn_exp2f(x);   // v_exp_f32
#else
    return __ocml_exp2_f32(x);
#endif
}
__device__ __forceinline__ float fast_rcp(float x) {
#if __has_builtin(__builtin_amdgcn_rcpf)
    return __builtin_amdgcn_rcpf(x);    // v_rcp_f32
#else
    return 1.0f / x;
#endif
}

__device__ __forceinline__ float4 fma4(float4 w, float x, float4 a) {
    a.x = fmaf(w.x, x, a.x); a.y = fmaf(w.y, x, a.y);
    a.z = fmaf(w.z, x, a.z); a.w = fmaf(w.w, x, a.w);
    return a;
}

// ---------------------------------------------------------------------------
// K1 v2: projections. Block = 16 rows x 128-h half. Grid 476:
//   blk 0..399  : enc  (200 row-chunks x 2 h-halves)
//   blk 400..475: dec  (38 row-chunks x 2 h-halves; last chunk ragged)
// Thread (h4 = tid&31, rg = tid>>5): 2 rows x 4 h accumulators.
// Weights read directly from global as float4 (L1 absorbs intra-block dup).
// Inputs staged once in LDS (32 KB), read as wave-uniform broadcast float2.
// ---------------------------------------------------------------------------
__global__ __launch_bounds__(256) void proj_kernel(
    const float* __restrict__ enc, const float* __restrict__ dec,
    const float* __restrict__ W_enc, const float* __restrict__ b_enc,
    const float* __restrict__ W_dec, const float* __restrict__ b_dec,
    float* __restrict__ enc_p, float* __restrict__ dec_p)
{
    const int tid = threadIdx.x;
    const int blk = blockIdx.x;
    const float* in; const float* Wm; const float* bias; float* outp;
    int chunk, hh, nrows;
    if (blk < 400) { in = enc; Wm = W_enc; bias = b_enc; outp = enc_p;
                     chunk = blk >> 1; hh = blk & 1; nrows = B_ * T_; }
    else           { in = dec; Wm = W_dec; bias = b_dec; outp = dec_p;
                     chunk = (blk - 400) >> 1; hh = (blk - 400) & 1; nrows = B_ * U_; }
    const int row0 = chunk * 16;
    const int rmax = nrows - 1;

    __shared__ float ilds[16][D_];   // 32 KB
    #pragma unroll
    for (int k = 0; k < 8; ++k) {
        int idx = tid + 256 * k;
        int row = idx >> 7;           // 0..15
        int c4  = idx & 127;          // 0..127
        int gr  = row0 + row; if (gr > rmax) gr = rmax;
        *(float4*)&ilds[row][c4 * 4] =
            ((const float4*)(in + (size_t)gr * D_))[c4];
    }
    __syncthreads();

    const int h4 = tid & 31;          // 0..31 -> 4*h4 within the 128-h half
    const int rg = tid >> 5;          // 0..7  -> rows 2rg, 2rg+1
    const int hbase = hh * 128 + 4 * h4;

    const float* wbase = Wm + hbase;            // + e*H_ per e
    const float* i0 = &ilds[2 * rg][0];
    const float* i1 = &ilds[2 * rg + 1][0];

    float4 bias4 = *(const float4*)(bias + hbase);
    float4 a0 = bias4, a1 = bias4;

    #pragma unroll 4
    for (int e = 0; e < D_; e += 2) {
        float4 w0 = *(const float4*)(wbase + (size_t)e * H_);
        float4 w1 = *(const float4*)(wbase + (size_t)(e + 1) * H_);
        float2 x0 = *(const float2*)(i0 + e);
        float2 x1 = *(const float2*)(i1 + e);
        a0 = fma4(w0, x0.x, a0); a0 = fma4(w1, x0.y, a0);
        a1 = fma4(w0, x1.x, a1); a1 = fma4(w1, x1.y, a1);
    }

    a0.x *= ARG_SCALE; a0.y *= ARG_SCALE; a0.z *= ARG_SCALE; a0.w *= ARG_SCALE;
    a1.x *= ARG_SCALE; a1.y *= ARG_SCALE; a1.z *= ARG_SCALE; a1.w *= ARG_SCALE;

    const int r0g = row0 + 2 * rg, r1g = r0g + 1;
    if (r0g <= rmax) *(float4*)(outp + (size_t)r0g * H_ + hbase) = a0;
    if (r1g <= rmax) *(float4*)(outp + (size_t)r1g * H_ + hbase) = a1;
}

// ---------------------------------------------------------------------------
// K2 v2: scores. Block = 32t x 32u tile, thread (ty,tx) owns 2t x 2u:
//   t = t0 + 2ty, 2ty+1 ; u = u0 + tx, tx+16  (bank-collision-free pattern)
// acc = sum_h w[h] * rcp(1 + exp2(e'[t,h] + d'[u,h]))   (e',d' pre-scaled)
// True score = const(t) - 2*acc; constants cancel in the u-softmax.
// ---------------------------------------------------------------------------
__global__ __launch_bounds__(256) void score_kernel(
    const float* __restrict__ enc_p, const float* __restrict__ dec_p,
    const float* __restrict__ w_score, float* __restrict__ out)
{
    const int tid = threadIdx.x;
    const int ut = blockIdx.x, tt = blockIdx.y, b = blockIdx.z;

    __shared__ float eld[32][PADH];
    __shared__ float dld[32][PADH];
    __shared__ float wld[H_];

    if (tid < 64) ((float4*)wld)[tid] = ((const float4*)w_score)[tid];

    const int t0 = tt * 32, u0 = ut * 32;
    #pragma unroll
    for (int k = 0; k < 8; ++k) {
        int idx = tid + 256 * k;
        int row = idx >> 6;        // 0..31
        int f4  = idx & 63;        // 0..63
        float4 ev = ((const float4*)(enc_p + (size_t)(b * T_ + t0 + row) * H_))[f4];
        *(float4*)&eld[row][f4 * 4] = ev;
        int du = u0 + row; if (du > U_ - 1) du = U_ - 1;
        float4 dv = ((const float4*)(dec_p + (size_t)(b * U_ + du) * H_))[f4];
        *(float4*)&dld[row][f4 * 4] = dv;
    }
    __syncthreads();

    const int tx = tid & 15, ty = tid >> 4;
    const float* e0 = &eld[2 * ty][0];
    const float* e1 = &eld[2 * ty + 1][0];
    const float* d0 = &dld[tx][0];
    const float* d1 = &dld[tx + 16][0];

    float4 z = {0.f, 0.f, 0.f, 0.f};
    float4 acc00 = z, acc01 = z, acc10 = z, acc11 = z;

    #pragma unroll 4
    for (int h4 = 0; h4 < H_ / 4; ++h4) {
        float4 ea = *(const float4*)(e0 + 4 * h4);
        float4 eb = *(const float4*)(e1 + 4 * h4);
        float4 da = *(const float4*)(d0 + 4 * h4);
        float4 db = *(const float4*)(d1 + 4 * h4);
        float4 w  = *(const float4*)(wld + 4 * h4);

        acc00.x = fmaf(w.x, fast_rcp(1.f + fast_exp2(ea.x + da.x)), acc00.x);
        acc00.y = fmaf(w.y, fast_rcp(1.f + fast_exp2(ea.y + da.y)), acc00.y);
        acc00.z = fmaf(w.z, fast_rcp(1.f + fast_exp2(ea.z + da.z)), acc00.z);
        acc00.w = fmaf(w.w, fast_rcp(1.f + fast_exp2(ea.w + da.w)), acc00.w);

        acc01.x = fmaf(w.x, fast_rcp(1.f + fast_exp2(ea.x + db.x)), acc01.x);
        acc01.y = fmaf(w.y, fast_rcp(1.f + fast_exp2(ea.y + db.y)), acc01.y);
        acc01.z = fmaf(w.z, fast_rcp(1.f + fast_exp2(ea.z + db.z)), acc01.z);
        acc01.w = fmaf(w.w, fast_rcp(1.f + fast_exp2(ea.w + db.w)), acc01.w);

        acc10.x = fmaf(w.x, fast_rcp(1.f + fast_exp2(eb.x + da.x)), acc10.x);
        acc10.y = fmaf(w.y, fast_rcp(1.f + fast_exp2(eb.y + da.y)), acc10.y);
        acc10.z = fmaf(w.z, fast_rcp(1.f + fast_exp2(eb.z + da.z)), acc10.z);
        acc10.w = fmaf(w.w, fast_rcp(1.f + fast_exp2(eb.w + da.w)), acc10.w);

        acc11.x = fmaf(w.x, fast_rcp(1.f + fast_exp2(eb.x + db.x)), acc11.x);
        acc11.y = fmaf(w.y, fast_rcp(1.f + fast_exp2(eb.y + db.y)), acc11.y);
        acc11.z = fmaf(w.z, fast_rcp(1.f + fast_exp2(eb.z + db.z)), acc11.z);
        acc11.w = fmaf(w.w, fast_rcp(1.f + fast_exp2(eb.w + db.w)), acc11.w);
    }

    const float s00 = (acc00.x + acc00.y) + (acc00.z + acc00.w);
    const float s01 = (acc01.x + acc01.y) + (acc01.z + acc01.w);
    const float s10 = (acc10.x + acc10.y) + (acc10.z + acc10.w);
    const float s11 = (acc11.x + acc11.y) + (acc11.z + acc11.w);

    const int ta = t0 + 2 * ty, tb = ta + 1;
    const int ua = u0 + tx, ub = ua + 16;          // ua always < U_
    out[(size_t)(b * T_ + ta) * U_ + ua] = s00;
    out[(size_t)(b * T_ + tb) * U_ + ua] = s10;
    if (ub < U_) {
        out[(size_t)(b * T_ + ta) * U_ + ub] = s01;
        out[(size_t)(b * T_ + tb) * U_ + ub] = s11;
    }
}

// ---------------------------------------------------------------------------
// K3: in-place softmax over U=150 of z = -2*acc. One wave per row.
// ---------------------------------------------------------------------------
__global__ __launch_bounds__(256) void softmax_kernel(float* __restrict__ io)
{
    const int tid  = threadIdx.x;
    const int wave = tid >> 6, lane = tid & 63;
    const int row  = blockIdx.x * 4 + wave;       // 0..3199
    float* p = io + (size_t)row * U_;

    float s0 = p[lane];
    float s1 = p[lane + 64];
    const bool v2 = (lane + 128) < U_;
    float s2 = v2 ? p[lane + 128] : 0.f;

    float z0 = -2.f * s0, z1 = -2.f * s1;
    float z2 = v2 ? -2.f * s2 : -INFINITY;

    float m = fmaxf(fmaxf(z0, z1), z2);
    #pragma unroll
    for (int off = 32; off > 0; off >>= 1) m = fmaxf(m, __shfl_xor(m, off));

    float p0 = fast_exp2((z0 - m) * LOG2E_F);
    float p1 = fast_exp2((z1 - m) * LOG2E_F);
    float p2 = v2 ? fast_exp2((z2 - m) * LOG2E_F) : 0.f;

    float s = p0 + p1 + p2;
    #pragma unroll
    for (int off = 32; off > 0; off >>= 1) s += __shfl_xor(s, off);

    const float inv = 1.0f / s;   // IEEE divide for accuracy
    p[lane]       = p0 * inv;
    p[lane + 64]  = p1 * inv;
    if (v2) p[lane + 128] = p2 * inv;
}

// ---------------------------------------------------------------------------
extern "C" void kernel_launch(void* const* d_in, const int* in_sizes, int n_in,
                              void* d_out, int out_size, void* d_ws, size_t ws_size,
                              hipStream_t stream) {
    const float* enc     = (const float*)d_in[0];
    const float* dec     = (const float*)d_in[1];
    const float* W_enc   = (const float*)d_in[2];
    const float* b_enc   = (const float*)d_in[3];
    const float* W_dec   = (const float*)d_in[4];
    const float* b_dec   = (const float*)d_in[5];
    const float* w_score = (const float*)d_in[6];
    // d_in[7] = b_score: cancels in softmax, unused.

    float* enc_p = (float*)d_ws;                       // [B*T, H] scaled enc projection
    float* dec_p = enc_p + (size_t)B_ * T_ * H_;       // [B*U, H] scaled dec projection
    float* out   = (float*)d_out;

    proj_kernel<<<476, 256, 0, stream>>>(enc, dec, W_enc, b_enc, W_dec, b_dec, enc_p, dec_p);
    score_kernel<<<dim3(5, 25, 4), 256, 0, stream>>>(enc_p, dec_p, w_score, out);
    softmax_kernel<<<800, 256, 0, stream>>>(out);
}